// Round 12
// baseline (101.405 us; speedup 1.0000x reference)
//
#include <hip/hip_runtime.h>
#include <hip/hip_fp16.h>

#define IN_DIM 256
#define HID 128
#define ELLW 16
#define OVF_CAP 32768

using bf16x8 = __attribute__((ext_vector_type(8))) short;
using f32x4 = __attribute__((ext_vector_type(4))) float;

struct h8 { __half2 a, b, c, d; };  // 16B = 8 halves

__device__ __forceinline__ unsigned short f2bf(float f) {
    unsigned u = __float_as_uint(f);
    u += 0x7fffu + ((u >> 16) & 1u);  // RNE (inputs finite)
    return (unsigned short)(u >> 16);
}

// ---- DPP row_ror rotate-reductions over 16-lane groups (VALU pipe) ----
template <int CTRL>
__device__ __forceinline__ float dpp_rot(float x) {
    return __int_as_float(
        __builtin_amdgcn_update_dpp(0, __float_as_int(x), CTRL, 0xf, 0xf, false));
}
__device__ __forceinline__ float rsum16(float x) {
    x += dpp_rot<0x121>(x);
    x += dpp_rot<0x122>(x);
    x += dpp_rot<0x124>(x);
    x += dpp_rot<0x128>(x);
    return x;
}
__device__ __forceinline__ float rmax16(float x) {
    x = fmaxf(x, dpp_rot<0x121>(x));
    x = fmaxf(x, dpp_rot<0x122>(x));
    x = fmaxf(x, dpp_rot<0x124>(x));
    x = fmaxf(x, dpp_rot<0x128>(x));
    return x;
}

__device__ __forceinline__ float lrelu(float t) { return t > 0.f ? t : 0.2f * t; }

__device__ __forceinline__ void accum8(f32x4& a0, f32x4& a1, float a, const h8& hv) {
    const float2 f0 = __half22float2(hv.a);
    const float2 f1 = __half22float2(hv.b);
    const float2 f2 = __half22float2(hv.c);
    const float2 f3 = __half22float2(hv.d);
    a0[0] += a * f0.x; a0[1] += a * f0.y;
    a0[2] += a * f1.x; a0[3] += a * f1.y;
    a1[0] += a * f2.x; a1[1] += a * f2.y;
    a1[2] += a * f3.x; a1[3] += a * f3.y;
}

// epilogue: q = rsum16( relu(acc+bias)·dvec )
__device__ __forceinline__ float epilogue16(const f32x4& a0, const f32x4& a1,
                                            const float* __restrict__ bias,
                                            const float* __restrict__ dvec, int sl) {
    const f32x4 bb0 = *reinterpret_cast<const f32x4*>(bias + sl * 8);
    const f32x4 bb1 = *reinterpret_cast<const f32x4*>(bias + sl * 8 + 4);
    const f32x4 d0 = *reinterpret_cast<const f32x4*>(dvec + sl * 8);
    const f32x4 d1 = *reinterpret_cast<const f32x4*>(dvec + sl * 8 + 4);
    float q = 0.f;
#pragma unroll
    for (int i = 0; i < 4; ++i) {
        q += fmaxf(a0[i] + bb0[i], 0.f) * d0[i];
        q += fmaxf(a1[i] + bb1[i], 0.f) * d1[i];
    }
    return rsum16(q);
}

// ---------- weight transpose+convert: W[K][128] fp32 -> Wt[K/8][128][8] bf16 ----------
__device__ __forceinline__ void wt_cvt_one(const float* __restrict__ W,
                                           short* __restrict__ Wt, int idx) {
    const int kkblk = idx >> 10;
    const int n = (idx >> 3) & 127;
    const int t = idx & 7;
    const int k = (kkblk << 3) | t;
    Wt[idx] = (short)f2bf(W[(size_t)k * HID + n]);
}

// ====== K1: merged setup: weight cvt + wd/v2/c2 + zero deg/ell/ovf_cnt ======
__global__ __launch_bounds__(256) void setup_k(const float* __restrict__ lin_W,
                                               const float* __restrict__ lin_b,
                                               const float* __restrict__ conv_Ws,
                                               const float* __restrict__ Wd,
                                               const float* __restrict__ adv,
                                               short* __restrict__ wtl,
                                               short* __restrict__ wtc0,
                                               short* __restrict__ wtc5,
                                               float* __restrict__ wd_out,
                                               float* __restrict__ v2,
                                               float* __restrict__ c2,
                                               int* __restrict__ deg,
                                               int* __restrict__ ell,
                                               int* __restrict__ ovf_cnt, int NS, int zd) {
    const int b = blockIdx.x;
    if (b < 256) {
        const int idx = b * 256 + threadIdx.x;
        if (idx < 32768) {
            wt_cvt_one(lin_W, wtl, idx);
        } else if (idx < 49152) {
            wt_cvt_one(conv_Ws, wtc0, idx - 32768);
        } else {
            wt_cvt_one(conv_Ws + 5 * (size_t)HID * HID, wtc5, idx - 49152);
        }
    } else if (b == 256) {
        __shared__ float wd1s[HID];
        const int t = threadIdx.x;
        const int l = t >> 7, j = t & 127;
        const float* w = Wd + ((size_t)(l * 5) * HID + j) * HID;
        const float* a = adv + (size_t)(l * 5) * HID;
        float s = 0.f;
        for (int k = 0; k < HID; k += 4) {
            const float4 wv = *reinterpret_cast<const float4*>(w + k);
            const float4 av = *reinterpret_cast<const float4*>(a + k);
            s += wv.x * av.x + wv.y * av.y + wv.z * av.z + wv.w * av.w;
        }
        wd_out[t] = s;
        if (l == 0) wd1s[j] = s;
        __syncthreads();
        const float* wr = lin_W + 2 * (size_t)IN_DIM * HID + (size_t)t * HID;
        float p = 0.f;
        for (int k = 0; k < HID; k += 4) {
            const float4 wv = *reinterpret_cast<const float4*>(wr + k);
            p += wv.x * wd1s[k] + wv.y * wd1s[k + 1] + wv.z * wd1s[k + 2] +
                 wv.w * wd1s[k + 3];
        }
        v2[t] = p;
        if (t == 0) {
            const float* br = lin_b + 2 * HID;
            float q = 0.f;
            for (int k = 0; k < HID; ++k) q += br[k] * wd1s[k];
            c2[0] = q;
        }
        if (t == 1) ovf_cnt[0] = 0;
    } else if (b < 257 + zd) {
        const int i4 = ((b - 257) * 256 + threadIdx.x) * 4;
        if (i4 + 4 <= NS) {
            *reinterpret_cast<int4*>(deg + i4) = make_int4(0, 0, 0, 0);
        } else {
            for (int i = i4; i < NS; ++i) deg[i] = 0;
        }
    } else {
        const int total = NS * ELLW;
        const int i4 = ((b - 257 - zd) * 256 + threadIdx.x) * 4;
        if (i4 + 4 <= total) *reinterpret_cast<int4*>(ell + i4) = make_int4(0, 0, 0, 0);
    }
}

// ---------- MFMA GEMM body (shared by merged kernel) ----------
template <int K>
__device__ __forceinline__ void gemm_body(const float* __restrict__ A,
                                          const short* __restrict__ Wt,
                                          const float* __restrict__ bias,
                                          float* __restrict__ C, int N, int bid) {
    const int tid = threadIdx.x;
    const int w = tid >> 6;
    const int lane = tid & 63;
    const int m16 = lane & 15;
    const int kg = lane >> 4;

    const int arow = bid * 64 + w * 16 + m16;
    const bool ok = arow < N;

    f32x4 acc[8];
#pragma unroll
    for (int j = 0; j < 8; ++j) acc[j] = (f32x4){0.f, 0.f, 0.f, 0.f};

    for (int k0 = 0; k0 < K; k0 += 32) {
        bf16x8 af = {0, 0, 0, 0, 0, 0, 0, 0};
        if (ok) {
            const float* ap = A + (size_t)arow * K + k0 + kg * 8;
            const float4 f0 = *reinterpret_cast<const float4*>(ap);
            const float4 f1 = *reinterpret_cast<const float4*>(ap + 4);
            af[0] = (short)f2bf(f0.x); af[1] = (short)f2bf(f0.y);
            af[2] = (short)f2bf(f0.z); af[3] = (short)f2bf(f0.w);
            af[4] = (short)f2bf(f1.x); af[5] = (short)f2bf(f1.y);
            af[6] = (short)f2bf(f1.z); af[7] = (short)f2bf(f1.w);
        }
        const short* bbase = Wt + (((k0 >> 3) + kg) << 10);
#pragma unroll
        for (int j = 0; j < 8; ++j) {
            const bf16x8 bf = *reinterpret_cast<const bf16x8*>(bbase + ((j * 16 + m16) << 3));
            acc[j] = __builtin_amdgcn_mfma_f32_16x16x32_bf16(af, bf, acc[j], 0, 0, 0);
        }
    }

    const int rbase = bid * 64 + w * 16 + kg * 4;
    float bj[8];
#pragma unroll
    for (int j = 0; j < 8; ++j) bj[j] = bias ? bias[j * 16 + m16] : 0.f;
#pragma unroll
    for (int j = 0; j < 8; ++j)
#pragma unroll
        for (int r = 0; r < 4; ++r) {
            const int row = rbase + r;
            if (row < N) C[(size_t)row * HID + j * 16 + m16] = acc[j][r] + bj[j];
        }
}

// ====== K2: merged ELL build (edge-parallel) + QENT projection GEMM ======
__global__ __launch_bounds__(256) void build_gemm_k(const int* __restrict__ src,
                                                    const int* __restrict__ dst, int E,
                                                    int* __restrict__ deg,
                                                    int* __restrict__ ell,
                                                    int2* __restrict__ ovf,
                                                    int* __restrict__ ovf_cnt,
                                                    const float* __restrict__ A,
                                                    const short* __restrict__ Wt,
                                                    const float* __restrict__ bias,
                                                    float* __restrict__ C, int N, int eb) {
    if ((int)blockIdx.x < eb) {
        const int e = blockIdx.x * 256 + threadIdx.x;
        if (e < E) {
            const int d = dst[e], s = src[e];
            const int pos = atomicAdd(deg + d, 1);
            if (pos < ELLW) {
                ell[(size_t)d * ELLW + pos] = s;
            } else {
                const int oi = atomicAdd(ovf_cnt, 1);
                if (oi < OVF_CAP) ovf[oi] = make_int2(d, s);
            }
        }
    } else {
        gemm_body<IN_DIM>(A, Wt, bias, C, N, (int)blockIdx.x - eb);
    }
}

// ---------- K3: dual MFMA GEMM: hs[N][256](fp16) = A @ {Wt0|Wt1}, fused as1/as2 ----
__global__ __launch_bounds__(256) void gemm_dual_k(const float* __restrict__ A,
                                                   const short* __restrict__ Wt0,
                                                   const short* __restrict__ Wt1,
                                                   __half* __restrict__ C,
                                                   float* __restrict__ as1,
                                                   float* __restrict__ as2,
                                                   const float* __restrict__ a1v,
                                                   const float* __restrict__ a2v, int N) {
    const int tid = threadIdx.x;
    const int w = tid >> 6;
    const int lane = tid & 63;
    const int m16 = lane & 15;
    const int kg = lane >> 4;

    const int arow = blockIdx.x * 64 + w * 16 + m16;
    const bool ok = arow < N;

    f32x4 acc[16];
#pragma unroll
    for (int j = 0; j < 16; ++j) acc[j] = (f32x4){0.f, 0.f, 0.f, 0.f};

    for (int k0 = 0; k0 < HID; k0 += 32) {
        bf16x8 af = {0, 0, 0, 0, 0, 0, 0, 0};
        if (ok) {
            const float* ap = A + (size_t)arow * HID + k0 + kg * 8;
            const float4 f0 = *reinterpret_cast<const float4*>(ap);
            const float4 f1 = *reinterpret_cast<const float4*>(ap + 4);
            af[0] = (short)f2bf(f0.x); af[1] = (short)f2bf(f0.y);
            af[2] = (short)f2bf(f0.z); af[3] = (short)f2bf(f0.w);
            af[4] = (short)f2bf(f1.x); af[5] = (short)f2bf(f1.y);
            af[6] = (short)f2bf(f1.z); af[7] = (short)f2bf(f1.w);
        }
        const int boff = ((k0 >> 3) + kg) << 10;
        const short* b0 = Wt0 + boff;
        const short* b1 = Wt1 + boff;
#pragma unroll
        for (int j = 0; j < 8; ++j) {
            const bf16x8 bf0 = *reinterpret_cast<const bf16x8*>(b0 + ((j * 16 + m16) << 3));
            acc[j] = __builtin_amdgcn_mfma_f32_16x16x32_bf16(af, bf0, acc[j], 0, 0, 0);
            const bf16x8 bf1 = *reinterpret_cast<const bf16x8*>(b1 + ((j * 16 + m16) << 3));
            acc[j + 8] = __builtin_amdgcn_mfma_f32_16x16x32_bf16(af, bf1, acc[j + 8], 0, 0, 0);
        }
    }

    const int rbase = blockIdx.x * 64 + w * 16 + kg * 4;
#pragma unroll
    for (int j = 0; j < 16; ++j)
#pragma unroll
        for (int r = 0; r < 4; ++r) {
            const int row = rbase + r;
            if (row < N) C[(size_t)row * 256 + j * 16 + m16] = __float2half(acc[j][r]);
        }

    float p1[4] = {0.f, 0.f, 0.f, 0.f};
    float p2[4] = {0.f, 0.f, 0.f, 0.f};
#pragma unroll
    for (int j = 0; j < 8; ++j) {
        const float a1 = a1v[j * 16 + m16];
        const float a2 = a2v[j * 16 + m16];
#pragma unroll
        for (int r = 0; r < 4; ++r) {
            p1[r] += acc[j][r] * a1;
            p2[r] += acc[j + 8][r] * a2;
        }
    }
#pragma unroll
    for (int r = 0; r < 4; ++r) {
        p1[r] = rsum16(p1[r]);
        p2[r] = rsum16(p2[r]);
    }
    if (m16 == 0)
#pragma unroll
        for (int r = 0; r < 4; ++r) {
            const int row = rbase + r;
            if (row < N) {
                as1[row] = p1[r];
                as2[row] = p2[r];
            }
        }
}

// ====== K4: fused 2-layer GAT over ELL — shfl-free, pinned parallel loads ======
// Each lane holds ALL 16 src indices (static regs); softmax computed redundantly
// per lane in VALU; only cross-lane ops are the 3 DPP feature-reductions.
#define ELIST(OP) OP(0, e0.x) OP(1, e0.y) OP(2, e0.z) OP(3, e0.w) \
                  OP(4, e1.x) OP(5, e1.y) OP(6, e1.z) OP(7, e1.w) \
                  OP(8, e2.x) OP(9, e2.y) OP(10, e2.z) OP(11, e2.w) \
                  OP(12, e3.x) OP(13, e3.y) OP(14, e3.z) OP(15, e3.w)

__global__ __launch_bounds__(256, 2) void gat_fused_k(
    const int* __restrict__ deg_arr, const int* __restrict__ ell,
    const int2* __restrict__ ovf, const int* __restrict__ ovf_cnt_p,
    const float* __restrict__ x_span, const float* __restrict__ v2,
    const float* __restrict__ c2, const float* __restrict__ as1,
    const float* __restrict__ as2, const __half* __restrict__ hs,
    const float* __restrict__ b1, const float* __restrict__ wd2v,
    const float* __restrict__ b2, const float* __restrict__ outW,
    const float* __restrict__ outb, float* __restrict__ out, int Ndst) {
    const int gidx = blockIdx.x * blockDim.x + threadIdx.x;
    const int row = gidx >> 4;
    const int sl = threadIdx.x & 15;
    if (row >= Ndst) return;

    const int deg = deg_arr[row];

    if (deg <= ELLW) {
        // ---- issue ALL independent loads up front, pin with sched_barrier ----
        const int* erow = ell + (size_t)row * ELLW;
        const int4 e0 = *reinterpret_cast<const int4*>(erow);
        const int4 e1 = *reinterpret_cast<const int4*>(erow + 4);
        const int4 e2 = *reinterpret_cast<const int4*>(erow + 8);
        const int4 e3 = *reinterpret_cast<const int4*>(erow + 12);

        const float* xr = x_span + (size_t)row * IN_DIM + sl * 16;
        const float* vr = v2 + sl * 16;
        float4 xv[4], vv[4];
#pragma unroll
        for (int i = 0; i < 4; ++i) {
            xv[i] = *reinterpret_cast<const float4*>(xr + i * 4);
            vv[i] = *reinterpret_cast<const float4*>(vr + i * 4);
        }

#define DECL_AS(i, s) const float as1v_##i = as1[s]; const float as2v_##i = as2[s];
        ELIST(DECL_AS)
#undef DECL_AS
#define DECL_H1(i, s) \
        const h8 h1_##i = *reinterpret_cast<const h8*>(hs + (size_t)(s) * 256 + sl * 8);
        ELIST(DECL_H1)
#undef DECL_H1
        __builtin_amdgcn_sched_barrier(0);  // pin: all loads above issue before compute

        // ---- ad1 = x_span[row]·v2 + c2 ----
        float p = 0.f;
#pragma unroll
        for (int i = 0; i < 4; ++i)
            p += xv[i].x * vv[i].x + xv[i].y * vv[i].y + xv[i].z * vv[i].z +
                 xv[i].w * vv[i].w;
        const float ad1 = rsum16(p) + c2[0];

        // ---- layer-1 softmax, per-lane redundant (no max-shift; |e| < ~20) ----
        float dsum1 = 0.f;
#define AL1(i, s) \
        float al1_##i = (i < deg) ? __expf(lrelu(as1v_##i + ad1)) : 0.f; dsum1 += al1_##i;
        ELIST(AL1)
#undef AL1
        const float inv1 = 1.f / (dsum1 + 1e-16f);

        // ---- issue layer-2 h loads now (fly under L1 accumulate + epilogue) ----
#define DECL_H2(i, s) \
        const h8 h2_##i = \
            *reinterpret_cast<const h8*>(hs + (size_t)(s) * 256 + 128 + sl * 8);
        ELIST(DECL_H2)
#undef DECL_H2
        __builtin_amdgcn_sched_barrier(0);

        // ---- layer-1 accumulate + epilogue -> ad2 ----
        f32x4 acc0 = {0.f, 0.f, 0.f, 0.f}, acc1 = {0.f, 0.f, 0.f, 0.f};
#define ACC1(i, s) accum8(acc0, acc1, al1_##i * inv1, h1_##i);
        ELIST(ACC1)
#undef ACC1
        const float ad2 = epilogue16(acc0, acc1, b1, wd2v, sl);

        // ---- layer-2 softmax + accumulate + epilogue ----
        float dsum2 = 0.f;
#define AL2(i, s) \
        float al2_##i = (i < deg) ? __expf(lrelu(as2v_##i + ad2)) : 0.f; dsum2 += al2_##i;
        ELIST(AL2)
#undef AL2
        const float inv2 = 1.f / (dsum2 + 1e-16f);

        f32x4 bcc0 = {0.f, 0.f, 0.f, 0.f}, bcc1 = {0.f, 0.f, 0.f, 0.f};
#define ACC2(i, s) accum8(bcc0, bcc1, al2_##i * inv2, h2_##i);
        ELIST(ACC2)
#undef ACC2
        const float q = epilogue16(bcc0, bcc1, b2, outW, sl);
        if (sl == 0) out[row] = q + outb[0];
    } else {
        // ===== general path (deg > 16): 16 ELL entries + overflow list, max-shift =====
        const int grp = threadIdx.x & 48;
        const int ce = ell[(size_t)row * ELLW + sl];
        const float a1c = as1[ce];
        const float a2c = as2[ce];

        float p = 0.f;
        const float* xr = x_span + (size_t)row * IN_DIM + sl * 16;
        const float* vr = v2 + sl * 16;
#pragma unroll
        for (int i = 0; i < 4; ++i) {
            const float4 xv = *reinterpret_cast<const float4*>(xr + i * 4);
            const float4 vv = *reinterpret_cast<const float4*>(vr + i * 4);
            p += xv.x * vv.x + xv.y * vv.y + xv.z * vv.z + xv.w * vv.w;
        }
        float ad = rsum16(p) + c2[0];

        int oc = *ovf_cnt_p;
        if (oc > OVF_CAP) oc = OVF_CAP;
#pragma unroll
        for (int layer = 0; layer < 2; ++layer) {
            const float ac = layer ? a2c : a1c;
            const float* as_s = layer ? as2 : as1;
            const int hoff = layer ? HID : 0;
            const float* bias = layer ? b2 : b1;
            const float* dvec = layer ? outW : wd2v;

            float te = lrelu(ac + ad);
            float m = rmax16(te);
            for (int i = 0; i < oc; ++i) {
                const int2 o = ovf[i];
                if (o.x == row) m = fmaxf(m, lrelu(as_s[o.y] + ad));
            }
            const float ex = __expf(te - m);
            float dsum = rsum16(ex);
            for (int i = 0; i < oc; ++i) {
                const int2 o = ovf[i];
                if (o.x == row) dsum += __expf(lrelu(as_s[o.y] + ad) - m);
            }
            const float inv = 1.f / (dsum + 1e-16f);
            const float al = ex * inv;

            f32x4 acc0 = {0.f, 0.f, 0.f, 0.f}, acc1 = {0.f, 0.f, 0.f, 0.f};
#pragma unroll
            for (int i = 0; i < 16; ++i) {
                const int s = __shfl(ce, grp | i, 64);
                const float a = __shfl(al, grp | i, 64);
                const h8 hv =
                    *reinterpret_cast<const h8*>(hs + (size_t)s * 256 + hoff + sl * 8);
                accum8(acc0, acc1, a, hv);
            }
            for (int i = 0; i < oc; ++i) {
                const int2 o = ovf[i];
                if (o.x == row) {
                    const float a = __expf(lrelu(as_s[o.y] + ad) - m) * inv;
                    const h8 hv =
                        *reinterpret_cast<const h8*>(hs + (size_t)o.y * 256 + hoff + sl * 8);
                    accum8(acc0, acc1, a, hv);
                }
            }
            const float q = epilogue16(acc0, acc1, bias, dvec, sl);
            if (layer == 0) {
                ad = q;
            } else if (sl == 0) {
                out[row] = q + outb[0];
            }
        }
    }
}

extern "C" void kernel_launch(void* const* d_in, const int* in_sizes, int n_in,
                              void* d_out, int out_size, void* d_ws, size_t ws_size,
                              hipStream_t stream) {
    // Live dataflow: out = relu(gat2)·outW + outb over QENT->SPAN only (see R4/R5).
    const float* x_qent = (const float*)d_in[0];
    const float* x_span = (const float*)d_in[2];
    const int* e_qs = (const int*)d_in[4];  // [2][E]
    const float* lin_W = (const float*)d_in[9];
    const float* lin_b = (const float*)d_in[10];
    const float* conv_Ws = (const float*)d_in[11];
    const float* conv_Wd = (const float*)d_in[12];
    const float* conv_as = (const float*)d_in[13];
    const float* conv_ad = (const float*)d_in[14];
    const float* conv_b = (const float*)d_in[15];
    const float* out_W = (const float*)d_in[16];
    const float* out_b = (const float*)d_in[17];

    const int NQ = in_sizes[0] / IN_DIM;
    const int NS = in_sizes[2] / IN_DIM;
    const int E = in_sizes[4] / 2;
    const int* srcp = e_qs;
    const int* dstp = e_qs + E;
    (void)n_in; (void)out_size;

    // ---- workspace carve (16B-aligned slots) ----
    float* ws = (float*)d_ws;
    size_t off = 0;
    auto alloc = [&](size_t n) {
        n = (n + 3) & ~(size_t)3;
        float* p = ws + off;
        off += n;
        return p;
    };
    float* xq = alloc((size_t)NQ * HID);
    __half* hs = (__half*)alloc((size_t)NQ * 128);  // fp16 [NQ][256]
    float* as1 = alloc(NQ);
    float* as2 = alloc(NQ);
    float* wd2 = alloc(2 * HID);
    float* v2 = alloc(IN_DIM);
    float* c2 = alloc(1);
    int* deg = (int*)alloc(NS);
    int* ell = (int*)alloc((size_t)NS * ELLW);
    int2* ovf = (int2*)alloc(2 * OVF_CAP);
    int* ovf_cnt = (int*)alloc(1);
    short* wt_lin0 = (short*)alloc(IN_DIM * HID / 2);
    short* wt_conv0 = (short*)alloc(HID * HID / 2);
    short* wt_conv5 = (short*)alloc(HID * HID / 2);
    (void)ws_size;

    // K1: setup (weight cvt + wd/v2/c2 + zero deg/ell/ovf_cnt)
    const int zd = (NS + 1023) / 1024;
    const int ze = (NS * ELLW + 1023) / 1024;
    setup_k<<<dim3(257 + zd + ze), dim3(256), 0, stream>>>(
        lin_W, lin_b, conv_Ws, conv_Wd, conv_ad, wt_lin0, wt_conv0, wt_conv5, wd2, v2, c2,
        deg, ell, ovf_cnt, NS, zd);

    // K2: ELL build (edge-parallel) + QENT projection, merged
    const int eb = (E + 255) / 256;
    const int gb = (NQ + 63) / 64;
    build_gemm_k<<<dim3(eb + gb), dim3(256), 0, stream>>>(
        srcp, dstp, E, deg, ell, ovf, ovf_cnt, x_qent, wt_lin0, lin_b, xq, NQ, eb);

    // K3: both layers' hs (fp16) + fused as1/as2
    gemm_dual_k<<<dim3(gb), dim3(256), 0, stream>>>(
        xq, wt_conv0, wt_conv5, hs, as1, as2, conv_as, conv_as + 5 * (size_t)HID, NQ);

    // K4: fused ad1 + 2-layer GAT + final projection
    gat_fused_k<<<dim3(((size_t)NS * 16 + 255) / 256), dim3(256), 0, stream>>>(
        deg, ell, ovf, ovf_cnt, x_span, v2, c2, as1, as2, hs, conv_b, wd2 + HID,
        conv_b + 5 * (size_t)HID, out_W, out_b, (float*)d_out, NS);
}

// Round 13
// 86.627 us; speedup vs baseline: 1.1706x; 1.1706x over previous
//
#include <hip/hip_runtime.h>
#include <hip/hip_fp16.h>

#define IN_DIM 256
#define HID 128
#define ELLW 16
#define OVF_CAP 32768

using bf16x8 = __attribute__((ext_vector_type(8))) short;
using f32x4 = __attribute__((ext_vector_type(4))) float;

struct h8 { __half2 a, b, c, d; };  // 16B = 8 halves

__device__ __forceinline__ unsigned short f2bf(float f) {
    unsigned u = __float_as_uint(f);
    u += 0x7fffu + ((u >> 16) & 1u);  // RNE (inputs finite)
    return (unsigned short)(u >> 16);
}

// ---- DPP row_ror rotate-reductions over 16-lane groups (VALU pipe) ----
template <int CTRL>
__device__ __forceinline__ float dpp_rot(float x) {
    return __int_as_float(
        __builtin_amdgcn_update_dpp(0, __float_as_int(x), CTRL, 0xf, 0xf, false));
}
__device__ __forceinline__ float rsum16(float x) {
    x += dpp_rot<0x121>(x);
    x += dpp_rot<0x122>(x);
    x += dpp_rot<0x124>(x);
    x += dpp_rot<0x128>(x);
    return x;
}
__device__ __forceinline__ float rmax16(float x) {
    x = fmaxf(x, dpp_rot<0x121>(x));
    x = fmaxf(x, dpp_rot<0x122>(x));
    x = fmaxf(x, dpp_rot<0x124>(x));
    x = fmaxf(x, dpp_rot<0x128>(x));
    return x;
}

__device__ __forceinline__ float lrelu(float t) { return t > 0.f ? t : 0.2f * t; }

__device__ __forceinline__ void accum8(f32x4& a0, f32x4& a1, float a, const h8& hv) {
    const float2 f0 = __half22float2(hv.a);
    const float2 f1 = __half22float2(hv.b);
    const float2 f2 = __half22float2(hv.c);
    const float2 f3 = __half22float2(hv.d);
    a0[0] += a * f0.x; a0[1] += a * f0.y;
    a0[2] += a * f1.x; a0[3] += a * f1.y;
    a1[0] += a * f2.x; a1[1] += a * f2.y;
    a1[2] += a * f3.x; a1[3] += a * f3.y;
}

// epilogue: q = rsum16( relu(acc+bias)·dvec )
__device__ __forceinline__ float epilogue16(const f32x4& a0, const f32x4& a1,
                                            const float* __restrict__ bias,
                                            const float* __restrict__ dvec, int sl) {
    const f32x4 bb0 = *reinterpret_cast<const f32x4*>(bias + sl * 8);
    const f32x4 bb1 = *reinterpret_cast<const f32x4*>(bias + sl * 8 + 4);
    const f32x4 d0 = *reinterpret_cast<const f32x4*>(dvec + sl * 8);
    const f32x4 d1 = *reinterpret_cast<const f32x4*>(dvec + sl * 8 + 4);
    float q = 0.f;
#pragma unroll
    for (int i = 0; i < 4; ++i) {
        q += fmaxf(a0[i] + bb0[i], 0.f) * d0[i];
        q += fmaxf(a1[i] + bb1[i], 0.f) * d1[i];
    }
    return rsum16(q);
}

// ====== K1: setup: collapsed weights (linW0@Wc_l) + bcomb + wd/v2/c2 + zeroing ======
__global__ __launch_bounds__(256) void setup_k(const float* __restrict__ lin_W,
                                               const float* __restrict__ lin_b,
                                               const float* __restrict__ conv_Ws,
                                               const float* __restrict__ Wd,
                                               const float* __restrict__ adv,
                                               short* __restrict__ wt0,
                                               short* __restrict__ wt1,
                                               float* __restrict__ bc,   // [2][128]
                                               float* __restrict__ wd_out,
                                               float* __restrict__ v2,
                                               float* __restrict__ c2,
                                               int* __restrict__ deg,
                                               int* __restrict__ ell,
                                               int* __restrict__ ovf_cnt, int NS, int zd) {
    const int b = blockIdx.x;
    if (b < 256) {
        // Wcomb[l][k][n] = sum_m linW0[k][m] * Wc_l[m][n]; store bf16 ELL-layout
        const int idx = b * 256 + threadIdx.x;  // [0, 65536)
        const int l = idx >> 15;
        const int rem = idx & 32767;
        const int k = rem >> 7;
        const int n = rem & 127;
        const float* lw = lin_W + (size_t)k * HID;  // linW0 row k
        const float* cw = conv_Ws + (size_t)(l * 5) * HID * HID + n;
        float s = 0.f;
#pragma unroll 4
        for (int m = 0; m < HID; ++m) s += lw[m] * cw[(size_t)m * HID];
        short* wt = l ? wt1 : wt0;
        wt[((k >> 3) << 10) + (n << 3) + (k & 7)] = (short)f2bf(s);
    } else if (b == 256) {
        // bcomb[l][n] = sum_m lin_b0[m] * Wc_l[m][n]
        const int t = threadIdx.x;
        const int l = t >> 7;
        const int n = t & 127;
        const float* cw = conv_Ws + (size_t)(l * 5) * HID * HID + n;
        float s = 0.f;
#pragma unroll 4
        for (int m = 0; m < HID; ++m) s += lin_b[m] * cw[(size_t)m * HID];
        bc[t] = s;
        if (t == 0) ovf_cnt[0] = 0;
    } else if (b == 257) {
        __shared__ float wd1s[HID];
        const int t = threadIdx.x;
        const int l = t >> 7, j = t & 127;
        const float* w = Wd + ((size_t)(l * 5) * HID + j) * HID;
        const float* a = adv + (size_t)(l * 5) * HID;
        float s = 0.f;
        for (int k = 0; k < HID; k += 4) {
            const float4 wv = *reinterpret_cast<const float4*>(w + k);
            const float4 av = *reinterpret_cast<const float4*>(a + k);
            s += wv.x * av.x + wv.y * av.y + wv.z * av.z + wv.w * av.w;
        }
        wd_out[t] = s;
        if (l == 0) wd1s[j] = s;
        __syncthreads();
        const float* wr = lin_W + 2 * (size_t)IN_DIM * HID + (size_t)t * HID;
        float p = 0.f;
        for (int k = 0; k < HID; k += 4) {
            const float4 wv = *reinterpret_cast<const float4*>(wr + k);
            p += wv.x * wd1s[k] + wv.y * wd1s[k + 1] + wv.z * wd1s[k + 2] +
                 wv.w * wd1s[k + 3];
        }
        v2[t] = p;
        if (t == 0) {
            const float* br = lin_b + 2 * HID;
            float q = 0.f;
            for (int k = 0; k < HID; ++k) q += br[k] * wd1s[k];
            c2[0] = q;
        }
    } else if (b < 258 + zd) {
        const int i4 = ((b - 258) * 256 + threadIdx.x) * 4;
        if (i4 + 4 <= NS) {
            *reinterpret_cast<int4*>(deg + i4) = make_int4(0, 0, 0, 0);
        } else {
            for (int i = i4; i < NS; ++i) deg[i] = 0;
        }
    } else {
        const int total = NS * ELLW;
        const int i4 = ((b - 258 - zd) * 256 + threadIdx.x) * 4;
        if (i4 + 4 <= total) *reinterpret_cast<int4*>(ell + i4) = make_int4(0, 0, 0, 0);
    }
}

// ====== K2: merged ELL build + dual K=256 GEMM from x_qent ======
// hs layout (half idx): row*256 + sl*16 + l*8 + t  (lane sl: feats sl*8+t, layer l)
__global__ __launch_bounds__(256) void build_gemm_k(
    const int* __restrict__ src, const int* __restrict__ dst, int E,
    int* __restrict__ deg, int* __restrict__ ell, int2* __restrict__ ovf,
    int* __restrict__ ovf_cnt, const float* __restrict__ A,
    const short* __restrict__ Wt0, const short* __restrict__ Wt1,
    const float* __restrict__ bc, __half* __restrict__ hs,
    float2* __restrict__ as12, const float* __restrict__ a1v,
    const float* __restrict__ a2v, int N, int eb) {
    if ((int)blockIdx.x < eb) {
        const int e = blockIdx.x * 256 + threadIdx.x;
        if (e < E) {
            const int d = dst[e], s = src[e];
            const int pos = atomicAdd(deg + d, 1);
            if (pos < ELLW) {
                ell[(size_t)d * ELLW + pos] = s;
            } else {
                const int oi = atomicAdd(ovf_cnt, 1);
                if (oi < OVF_CAP) ovf[oi] = make_int2(d, s);
            }
        }
        return;
    }
    const int bid = (int)blockIdx.x - eb;
    const int tid = threadIdx.x;
    const int w = tid >> 6;
    const int lane = tid & 63;
    const int m16 = lane & 15;
    const int kg = lane >> 4;

    const int arow = bid * 64 + w * 16 + m16;
    const bool ok = arow < N;

    f32x4 acc[16];
#pragma unroll
    for (int j = 0; j < 16; ++j) acc[j] = (f32x4){0.f, 0.f, 0.f, 0.f};

    for (int k0 = 0; k0 < IN_DIM; k0 += 32) {
        bf16x8 af = {0, 0, 0, 0, 0, 0, 0, 0};
        if (ok) {
            const float* ap = A + (size_t)arow * IN_DIM + k0 + kg * 8;
            const float4 f0 = *reinterpret_cast<const float4*>(ap);
            const float4 f1 = *reinterpret_cast<const float4*>(ap + 4);
            af[0] = (short)f2bf(f0.x); af[1] = (short)f2bf(f0.y);
            af[2] = (short)f2bf(f0.z); af[3] = (short)f2bf(f0.w);
            af[4] = (short)f2bf(f1.x); af[5] = (short)f2bf(f1.y);
            af[6] = (short)f2bf(f1.z); af[7] = (short)f2bf(f1.w);
        }
        const int boff = ((k0 >> 3) + kg) << 10;
        const short* b0 = Wt0 + boff;
        const short* b1 = Wt1 + boff;
#pragma unroll
        for (int j = 0; j < 8; ++j) {
            const bf16x8 bf0 = *reinterpret_cast<const bf16x8*>(b0 + ((j * 16 + m16) << 3));
            acc[j] = __builtin_amdgcn_mfma_f32_16x16x32_bf16(af, bf0, acc[j], 0, 0, 0);
            const bf16x8 bf1 = *reinterpret_cast<const bf16x8*>(b1 + ((j * 16 + m16) << 3));
            acc[j + 8] = __builtin_amdgcn_mfma_f32_16x16x32_bf16(af, bf1, acc[j + 8], 0, 0, 0);
        }
    }

    const int rbase = bid * 64 + w * 16 + kg * 4;
    float p1[4] = {0.f, 0.f, 0.f, 0.f};
    float p2[4] = {0.f, 0.f, 0.f, 0.f};
#pragma unroll
    for (int j = 0; j < 8; ++j) {
        const int col = j * 16 + m16;
        const float b0v = bc[col];
        const float b1v = bc[128 + col];
        const float a1 = a1v[col];
        const float a2 = a2v[col];
        // interleaved store offset: row*256 + j*32 + (m16>>3)*16 + l*8 + (m16&7)
        const int so = j * 32 + ((m16 >> 3) << 4) + (m16 & 7);
#pragma unroll
        for (int r = 0; r < 4; ++r) {
            const int row = rbase + r;
            const float v1 = acc[j][r] + b0v;
            const float v2v = acc[j + 8][r] + b1v;
            if (row < N) {
                hs[(size_t)row * 256 + so] = __float2half(v1);
                hs[(size_t)row * 256 + so + 8] = __float2half(v2v);
            }
            p1[r] += v1 * a1;
            p2[r] += v2v * a2;
        }
    }
#pragma unroll
    for (int r = 0; r < 4; ++r) {
        p1[r] = rsum16(p1[r]);
        p2[r] = rsum16(p2[r]);
    }
    if (m16 == 0)
#pragma unroll
        for (int r = 0; r < 4; ++r) {
            const int row = rbase + r;
            if (row < N) as12[row] = make_float2(p1[r], p2[r]);
        }
}

// ====== K3: fused 2-layer GAT over ELL (R11 structure, interleaved-h layout) ======
__global__ __launch_bounds__(256, 4) void gat_fused_k(
    const int* __restrict__ deg_arr, const int* __restrict__ ell,
    const int2* __restrict__ ovf, const int* __restrict__ ovf_cnt_p,
    const float* __restrict__ x_span, const float* __restrict__ v2,
    const float* __restrict__ c2, const float2* __restrict__ as12,
    const __half* __restrict__ hs, const float* __restrict__ b1,
    const float* __restrict__ wd2v, const float* __restrict__ b2,
    const float* __restrict__ outW, const float* __restrict__ outb,
    float* __restrict__ out, int Ndst) {
    const int gidx = blockIdx.x * blockDim.x + threadIdx.x;
    const int row = gidx >> 4;
    const int sl = threadIdx.x & 15;
    const int grp = threadIdx.x & 48;
    if (row >= Ndst) return;

    const int deg = deg_arr[row];
    const int ce = ell[(size_t)row * ELLW + sl];  // zero-padded beyond deg

    // ---- ad1 = x_span[row]·v2 + c2 ----
    float p = 0.f;
    const float* xr = x_span + (size_t)row * IN_DIM + sl * 16;
    const float* vr = v2 + sl * 16;
#pragma unroll
    for (int i = 0; i < 4; ++i) {
        const float4 xv = *reinterpret_cast<const float4*>(xr + i * 4);
        const float4 vv = *reinterpret_cast<const float4*>(vr + i * 4);
        p += xv.x * vv.x + xv.y * vv.y + xv.z * vv.z + xv.w * vv.w;
    }
    const float ad1 = rsum16(p) + c2[0];

    const float2 asv = as12[ce];
    const float a1c = asv.x;
    const float a2c = asv.y;

    // ---- preload h for first 8 edges, BOTH layers (same 64B line per edge) ----
    h8 h1[8], h2[8];
#pragma unroll
    for (int i = 0; i < 8; ++i) {
        const int s = __shfl(ce, grp | i, 64);
        const __half* hb = hs + (size_t)s * 256 + sl * 16;
        h1[i] = *reinterpret_cast<const h8*>(hb);
        h2[i] = *reinterpret_cast<const h8*>(hb + 8);
    }

    if (deg <= ELLW) {
        // ===== layer 1 (no max-shift; |score| <~ 20, exp safe in fp32) =====
        const float ex1 = (sl < deg) ? __expf(lrelu(a1c + ad1)) : 0.f;
        const float al1 = ex1 / (rsum16(ex1) + 1e-16f);

        f32x4 acc0 = {0.f, 0.f, 0.f, 0.f}, acc1 = {0.f, 0.f, 0.f, 0.f};
#pragma unroll
        for (int i = 0; i < 8; ++i) {
            const float a = __shfl(al1, grp | i, 64);  // 0 for i >= deg
            accum8(acc0, acc1, a, h1[i]);
        }
        for (int i = 8; i < deg; ++i) {
            const int s = __shfl(ce, grp | i, 64);
            const float a = __shfl(al1, grp | i, 64);
            const h8 hv = *reinterpret_cast<const h8*>(hs + (size_t)s * 256 + sl * 16);
            accum8(acc0, acc1, a, hv);
        }
        const float ad2 = epilogue16(acc0, acc1, b1, wd2v, sl);

        // ===== layer 2 (h2 already in registers for first 8 edges) =====
        const float ex2 = (sl < deg) ? __expf(lrelu(a2c + ad2)) : 0.f;
        const float al2 = ex2 / (rsum16(ex2) + 1e-16f);

        f32x4 bcc0 = {0.f, 0.f, 0.f, 0.f}, bcc1 = {0.f, 0.f, 0.f, 0.f};
#pragma unroll
        for (int i = 0; i < 8; ++i) {
            const float a = __shfl(al2, grp | i, 64);
            accum8(bcc0, bcc1, a, h2[i]);
        }
        for (int i = 8; i < deg; ++i) {
            const int s = __shfl(ce, grp | i, 64);
            const float a = __shfl(al2, grp | i, 64);
            const h8 hv = *reinterpret_cast<const h8*>(hs + (size_t)s * 256 + sl * 16 + 8);
            accum8(bcc0, bcc1, a, hv);
        }
        const float q = epilogue16(bcc0, bcc1, b2, outW, sl);
        if (sl == 0) out[row] = q + outb[0];
    } else {
        // ===== general path (deg > 16): ELL entries + overflow list, max-shift =====
        int oc = *ovf_cnt_p;
        if (oc > OVF_CAP) oc = OVF_CAP;
        float ad = ad1;
#pragma unroll
        for (int layer = 0; layer < 2; ++layer) {
            const float ac = layer ? a2c : a1c;
            const int ho = layer ? 8 : 0;
            const float* bias = layer ? b2 : b1;
            const float* dvec = layer ? outW : wd2v;

            float te = lrelu(ac + ad);
            float m = rmax16(te);
            for (int i = 0; i < oc; ++i) {
                const int2 o = ovf[i];
                if (o.x == row) {
                    const float2 oas = as12[o.y];
                    m = fmaxf(m, lrelu((layer ? oas.y : oas.x) + ad));
                }
            }
            const float ex = __expf(te - m);
            float dsum = rsum16(ex);
            for (int i = 0; i < oc; ++i) {
                const int2 o = ovf[i];
                if (o.x == row) {
                    const float2 oas = as12[o.y];
                    dsum += __expf(lrelu((layer ? oas.y : oas.x) + ad) - m);
                }
            }
            const float inv = 1.f / (dsum + 1e-16f);
            const float al = ex * inv;

            f32x4 acc0 = {0.f, 0.f, 0.f, 0.f}, acc1 = {0.f, 0.f, 0.f, 0.f};
#pragma unroll
            for (int i = 0; i < 16; ++i) {
                const int s = __shfl(ce, grp | i, 64);
                const float a = __shfl(al, grp | i, 64);
                const h8 hv =
                    *reinterpret_cast<const h8*>(hs + (size_t)s * 256 + sl * 16 + ho);
                accum8(acc0, acc1, a, hv);
            }
            for (int i = 0; i < oc; ++i) {
                const int2 o = ovf[i];
                if (o.x == row) {
                    const float2 oas = as12[o.y];
                    const float a = __expf(lrelu((layer ? oas.y : oas.x) + ad) - m) * inv;
                    const h8 hv =
                        *reinterpret_cast<const h8*>(hs + (size_t)o.y * 256 + sl * 16 + ho);
                    accum8(acc0, acc1, a, hv);
                }
            }
            const float q = epilogue16(acc0, acc1, bias, dvec, sl);
            if (layer == 0) {
                ad = q;
            } else if (sl == 0) {
                out[row] = q + outb[0];
            }
        }
    }
}

extern "C" void kernel_launch(void* const* d_in, const int* in_sizes, int n_in,
                              void* d_out, int out_size, void* d_ws, size_t ws_size,
                              hipStream_t stream) {
    // Live dataflow: out = relu(gat2)·outW + outb over QENT->SPAN only (see R4/R5).
    const float* x_qent = (const float*)d_in[0];
    const float* x_span = (const float*)d_in[2];
    const int* e_qs = (const int*)d_in[4];  // [2][E]
    const float* lin_W = (const float*)d_in[9];
    const float* lin_b = (const float*)d_in[10];
    const float* conv_Ws = (const float*)d_in[11];
    const float* conv_Wd = (const float*)d_in[12];
    const float* conv_as = (const float*)d_in[13];
    const float* conv_ad = (const float*)d_in[14];
    const float* conv_b = (const float*)d_in[15];
    const float* out_W = (const float*)d_in[16];
    const float* out_b = (const float*)d_in[17];

    const int NQ = in_sizes[0] / IN_DIM;
    const int NS = in_sizes[2] / IN_DIM;
    const int E = in_sizes[4] / 2;
    const int* srcp = e_qs;
    const int* dstp = e_qs + E;
    (void)n_in; (void)out_size;

    // ---- workspace carve (16B-aligned slots) ----
    float* ws = (float*)d_ws;
    size_t off = 0;
    auto alloc = [&](size_t n) {
        n = (n + 3) & ~(size_t)3;
        float* p = ws + off;
        off += n;
        return p;
    };
    __half* hs = (__half*)alloc((size_t)NQ * 128);  // fp16 [NQ][256], layer-interleaved
    float2* as12 = (float2*)alloc(2 * (size_t)NQ);
    float* wd2 = alloc(2 * HID);
    float* v2 = alloc(IN_DIM);
    float* c2 = alloc(1);
    float* bc = alloc(2 * HID);
    int* deg = (int*)alloc(NS);
    int* ell = (int*)alloc((size_t)NS * ELLW);
    int2* ovf = (int2*)alloc(2 * OVF_CAP);
    int* ovf_cnt = (int*)alloc(1);
    short* wt0 = (short*)alloc(IN_DIM * HID / 2);
    short* wt1 = (short*)alloc(IN_DIM * HID / 2);
    (void)ws_size;

    // K1: setup (collapsed weights + bcomb + wd/v2/c2 + zero deg/ell/ovf_cnt)
    const int zd = (NS + 1023) / 1024;
    const int ze = (NS * ELLW + 1023) / 1024;
    setup_k<<<dim3(258 + zd + ze), dim3(256), 0, stream>>>(
        lin_W, lin_b, conv_Ws, conv_Wd, conv_ad, wt0, wt1, bc, wd2, v2, c2, deg, ell,
        ovf_cnt, NS, zd);

    // K2: ELL build (edge-parallel) + dual K=256 GEMM from x_qent, merged
    const int eb = (E + 255) / 256;
    const int gb = (NQ + 63) / 64;
    build_gemm_k<<<dim3(eb + gb), dim3(256), 0, stream>>>(
        srcp, dstp, E, deg, ell, ovf, ovf_cnt, x_qent, wt0, wt1, bc, hs, as12, conv_as,
        conv_as + 5 * (size_t)HID, NQ, eb);

    // K3: fused ad1 + 2-layer GAT + final projection
    gat_fused_k<<<dim3(((size_t)NS * 16 + 255) / 256), dim3(256), 0, stream>>>(
        deg, ell, ovf, ovf_cnt, x_span, v2, c2, as12, hs, conv_b, wd2 + HID,
        conv_b + 5 * (size_t)HID, out_W, out_b, (float*)d_out, NS);
}